// Round 6
// baseline (25.934 us; speedup 1.0000x reference)
//
#include <hip/hip_runtime.h>
#include <math.h>

// Problem constants (match reference)
constexpr int   BATCH = 32;
constexpr int   S     = 262144;
constexpr int   BLK   = 128;          // samples per filter block
constexpr int   NB    = S / BLK;      // 2048 blocks per batch row
constexpr float SRATE = 44100.0f;
constexpr float FC_MIN = 2000.0f, FC_MAX = 20000.0f;
constexpr float Q_MIN  = 0.1f,    Q_MAX  = 10.0f;

// 32 lanes cooperate on one audio block IN THE COALESCED DOMAIN (lane r owns
// samples 4r..4r+3 = one float4). No LDS, no barriers, every transaction
// coalesced. Biquad as linear state recurrence s' = M s + k x:
//   M = [[-a1, 1], [-a2, 0]],  k = (b1 - a1 b0, b2 - a2 b0)   (b2 == b0)
// Pass 1 (zero state) yields BOTH y_local and the local end-state u in the
// same 12 FMA. Kogge-Stone scan over 32 lanes with lane-uniform M^4 powers
// gives each lane its true incoming state z; output is then the linear
// correction y_n = y_local_n + row0(M^n)·z  (8 FMA, short dependent tail).
// sin/cos: w0 = 2*pi*fc/SR with fc/SR in [0.045, 0.45] -> hardware
// v_sin_f32/v_cos_f32 (input in revolutions), no libm, no arg reduction.

__global__ __launch_bounds__(256, 8) void lowpass_scan_kernel(
    const float4* __restrict__ x4,
    const float4* __restrict__ cp4,
    float4* __restrict__ o4,
    float* __restrict__ fc_out,
    float* __restrict__ q_out)
{
    const int tid  = blockIdx.x * blockDim.x + threadIdx.x;
    const int r    = tid & 31;             // chunk index within the block
    const int blkg = tid >> 5;             // global audio-block id, 0..65535
    const int b    = blkg >> 11;           // batch row (/ NB)
    const int blkL = blkg & (NB - 1);      // block within batch row

    // float4 indices (all perfectly coalesced across the wave)
    const size_t xi  = (size_t)blkg * 32 + r;                        // x / out
    const size_t c0i = (size_t)b * (2 * S / 4) + (size_t)blkL * 32 + r;

    const float4 xv  = x4[xi];
    const float4 c0v = cp4[c0i];
    const float4 c1v = cp4[c0i + S / 4];

    // ---- control means: tree reduce across the 32-lane segment ----------
    float s0 = (c0v.x + c0v.y) + (c0v.z + c0v.w);
    float s1 = (c1v.x + c1v.y) + (c1v.z + c1v.w);
#pragma unroll
    for (int m = 1; m < 32; m <<= 1) {     // masks <32: stays within segment
        s0 += __shfl_xor(s0, m);
        s1 += __shfl_xor(s1, m);
    }
    const float m0 = s0 * (1.0f / BLK);
    const float m1 = s1 * (1.0f / BLK);

    const float fc = m0 * (FC_MAX - FC_MIN) + FC_MIN;
    const float q  = m1 * (Q_MAX - Q_MIN) + Q_MIN;
    if (r == 0) {                          // one writer per block
        fc_out[blkg] = fc;
        q_out[blkg]  = q;
    }

    // ---- RBJ low-pass coefficients (hardware sin/cos, revolutions) -------
    const float rev = fc * (1.0f / SRATE);          // w0 / (2*pi), in [0.045,0.45]
    const float sw = __builtin_amdgcn_sinf(rev);    // sin(w0)
    const float cw = __builtin_amdgcn_cosf(rev);    // cos(w0)
    const float alpha = sw / (2.0f * q);
    const float a0inv = 1.0f / (1.0f + alpha);
    const float b0c = (1.0f - cw) * 0.5f * a0inv;   // b2 == b0
    const float b1c = (1.0f - cw) * a0inv;
    const float a1c = (-2.0f * cw) * a0inv;
    const float a2c = (1.0f - alpha) * a0inv;

    // ---- pass 1: DF2T from zero state -> y_local AND end-state u ---------
    float z1 = 0.0f, z2 = 0.0f;
    float4 yv;
    {
        float xn, y, z1n;
        xn = xv.x; y = b0c * xn + z1;
        z1n = b1c * xn - a1c * y + z2; z2 = b0c * xn - a2c * y; z1 = z1n; yv.x = y;
        xn = xv.y; y = b0c * xn + z1;
        z1n = b1c * xn - a1c * y + z2; z2 = b0c * xn - a2c * y; z1 = z1n; yv.y = y;
        xn = xv.z; y = b0c * xn + z1;
        z1n = b1c * xn - a1c * y + z2; z2 = b0c * xn - a2c * y; z1 = z1n; yv.z = y;
        xn = xv.w; y = b0c * xn + z1;
        z1n = b1c * xn - a1c * y + z2; z2 = b0c * xn - a2c * y; z1 = z1n; yv.w = y;
    }
    // u = (z1, z2): block-local state after this lane's 4 samples

    // ---- P = M^4 via two squarings of M ----------------------------------
    float P00 = -a1c, P01 = 1.0f, P10 = -a2c, P11 = 0.0f;
#define SQUARE_P()                                  \
    {   float q00 = P00 * P00 + P01 * P10;          \
        float q01 = P01 * (P00 + P11);              \
        float q10 = P10 * (P00 + P11);              \
        float q11 = P11 * P11 + P01 * P10;          \
        P00 = q00; P01 = q01; P10 = q10; P11 = q11; }
    SQUARE_P();   // M^2
    SQUARE_P();   // M^4

    // ---- Kogge-Stone inclusive scan: v_r = sum_{j<=r} P^(r-j) u_j --------
    float v1 = z1, v2 = z2;
#define SCAN_STEP(d)                                        \
    {   float w1 = __shfl_up(v1, d, 32);                    \
        float w2 = __shfl_up(v2, d, 32);                    \
        float t1 = v1 + P00 * w1 + P01 * w2;                \
        float t2 = v2 + P10 * w1 + P11 * w2;                \
        v1 = (r >= d) ? t1 : v1;                            \
        v2 = (r >= d) ? t2 : v2; }
    SCAN_STEP(1)  SQUARE_P();   // P -> M^8
    SCAN_STEP(2)  SQUARE_P();   // P -> M^16
    SCAN_STEP(4)  SQUARE_P();   // P -> M^32
    SCAN_STEP(8)
    SCAN_STEP(16)
#undef SCAN_STEP
#undef SQUARE_P

    // ---- exclusive shift: incoming state z for this lane's 4 samples -----
    float zi1 = __shfl_up(v1, 1, 32);
    float zi2 = __shfl_up(v2, 1, 32);
    if (r == 0) { zi1 = 0.0f; zi2 = 0.0f; }

    // ---- output correction: y_n += row0(M^n) · z -------------------------
    //   n=0: [1, 0]            n=1: [-a1, 1]
    //   n=2: [a1^2 - a2, -a1]  n=3: [-a1^3 + 2 a1 a2, a1^2 - a2]
    {
        const float c2 = a1c * a1c - a2c;          // a1^2 - a2
        const float c3 = -a1c * c2 + a1c * a2c;    // -a1^3 + 2 a1 a2
        yv.x += zi1;
        yv.y += -a1c * zi1 + zi2;
        yv.z +=   c2 * zi1 - a1c * zi2;
        yv.w +=   c3 * zi1 +   c2 * zi2;
    }
    o4[xi] = yv;
}

extern "C" void kernel_launch(void* const* d_in, const int* in_sizes, int n_in,
                              void* d_out, int out_size, void* d_ws, size_t ws_size,
                              hipStream_t stream) {
    const float4* x4  = (const float4*)d_in[0];   // (32, 1, 262144)
    const float4* cp4 = (const float4*)d_in[1];   // (32, 2, 262144)

    float* out    = (float*)d_out;                      // 32*262144
    float* fc_out = out + (size_t)BATCH * S;            // 32*2048
    float* q_out  = fc_out + (size_t)BATCH * NB;        // 32*2048

    // 32 lanes per audio block: 65536 blocks * 32 = 2,097,152 threads
    const int total_threads = BATCH * NB * 32;
    lowpass_scan_kernel<<<total_threads / 256, 256, 0, stream>>>(
        x4, cp4, (float4*)out, fc_out, q_out);
}